// Round 5
// baseline (11.397 us; speedup 1.0000x reference)
//
#include <hip/hip_runtime.h>
#include <stdint.h>

// KANRNNEncoder: T=1024 scan has dependency horizon 2 (only h[:, :24] feeds
// the recurrence, and those columns are pure functions of x at the previous
// step). Entire scan collapses to a closed form over x[:, T-2:T, :].
//
// R1: W_lat staged in LDS (coalesced), lane-rotated dot.      14.2 -> 10.4 us
// R2: K-split via MORE BLOCKS: REGRESSED (18.9) — per-block W staging is the
//     fixed cost; more waves must come from inside the block.
// R3: 512 thr (2 waves/SIMD), wave-pair K-split, gload_lds W.  -> 9.6 us
// R4: kill half the dot's LDS traffic: pad W rows to 260 floats so
//     UNROTATED per-lane row reads sit at the 1KB/instr bank floor, and read
//     hT with wave-uniform addresses (same-address broadcast = free).
//     Padded staging stays gload_lds-legal: one issue per 1024B row, dest
//     base at each padded row start + lane*16.

constexpr int Bc = 1024, Tc = 1024, Fc = 8, Hc = 256, Kc = 8, Lc = 64;
constexpr int WROW = 260;   // padded W row stride in floats (1040 B)

__device__ __forceinline__ float sigm(float v) {
    return 1.0f / (1.0f + __expf(-v));
}

__global__ __launch_bounds__(512) void kan_rnn_collapsed(
    const float* __restrict__ x,     // (B,T,F)
    const float* __restrict__ a_in,  // (F,K) flat 64
    const float* __restrict__ b_in,  // (F,K)
    const float* __restrict__ a_h,   // (H,K) flat 2048
    const float* __restrict__ b_h,   // (H,K)
    const float* __restrict__ W,     // (L,H) 64x256
    const float* __restrict__ bl,    // (L,)
    float* __restrict__ out)         // (B,L)
{
    __shared__ float Ws[Lc * WROW];  // 65 KB, padded rows
    __shared__ float hTs[4][Hc];     // 4 KB
    __shared__ float part[4][Lc];    // 1 KB
    const int t   = threadIdx.x;
    const int w   = t >> 6;          // wave 0..7
    const int l   = t & 63;          // lane
    const int rib = w >> 1;          // row-in-block 0..3
    const int kh  = w & 1;           // K-half 0..1
    const int b   = blockIdx.x * 4 + rib;

    // ---- async stage W -> LDS, one 1024B row per issue (pad between rows) ----
    {
        const char* gW = (const char*)W;
        char*       lW = (char*)&Ws[0];
        #pragma unroll
        for (int k = 0; k < 8; ++k) {
            const int r = w * 8 + k;     // wave-uniform row id
            __builtin_amdgcn_global_load_lds(
                (const __attribute__((address_space(1))) uint32_t*)(gW + r * 1024 + l * 16),
                (__attribute__((address_space(3))) uint32_t*)(lW + r * 1040 + l * 16),
                16, 0, 0);
        }
    }

    // ---- closed-form hT, split across the row's wave pair ----
    const float* xb  = x + (size_t)b * Tc * Fc;
    const int    hp0 = l >> 3;
    if (kh == 0) {   // entries c = l and c = 64+l   (m=0)
        const float x1  = xb[(Tc - 1) * Fc + hp0];
        const float x20 = xb[(Tc - 2) * Fc + 0];
        hTs[rib][l]      = sigm(2.0f * sigm(a_in[l]   * (x1  - b_in[l])));
        const float s0   = sigm(2.0f * sigm(a_in[hp0] * (x20 - b_in[hp0])));
        hTs[rib][64 + l] = sigm(2.0f * sigm(a_h[l]    * (s0  - b_h[l])));
    } else {         // entries c = 128+l (m=1) and c = 192+l (m=2)
        const float x21 = xb[(Tc - 2) * Fc + 1];
        const float x22 = xb[(Tc - 2) * Fc + 2];
        const int hp1 = hp0 + 8,  hp2 = hp0 + 16;
        const int j1  = l + 64,   j2  = l + 128;
        const float s1 = sigm(2.0f * sigm(a_in[hp1] * (x21 - b_in[hp1])));
        hTs[rib][64 + j1] = sigm(2.0f * sigm(a_h[j1] * (s1 - b_h[j1])));
        const float s2 = sigm(2.0f * sigm(a_in[hp2] * (x22 - b_in[hp2])));
        hTs[rib][64 + j2] = sigm(2.0f * sigm(a_h[j2] * (s2 - b_h[j2])));
    }
    __syncthreads();   // drains gload_lds (vmcnt) + hT writes (lgkm)

    // ---- half-dot: lane l accumulates W[l][K-half] . hT[rib][K-half] ----
    // Uniform chunk index q across lanes:
    //   wv: per-lane row (stride 260 floats) -> start bank (4l+4q)%32,
    //       8 lanes per 4-bank group = the 1KB/instr BW floor, no excess.
    //   hv: same address across all lanes -> LDS broadcast, ~free.
    const float4* Wrow = reinterpret_cast<const float4*>(Ws + l * WROW);
    const float4* hrow = reinterpret_cast<const float4*>(hTs[rib]);
    const int qb = 32 * kh;
    float a0 = 0.f, a1 = 0.f, a2 = 0.f, a3 = 0.f;
    #pragma unroll
    for (int i = 0; i < 32; i += 4) {
        float4 wv, hv;
        wv = Wrow[qb + i + 0]; hv = hrow[qb + i + 0];
        a0 += wv.x * hv.x + wv.y * hv.y + wv.z * hv.z + wv.w * hv.w;
        wv = Wrow[qb + i + 1]; hv = hrow[qb + i + 1];
        a1 += wv.x * hv.x + wv.y * hv.y + wv.z * hv.z + wv.w * hv.w;
        wv = Wrow[qb + i + 2]; hv = hrow[qb + i + 2];
        a2 += wv.x * hv.x + wv.y * hv.y + wv.z * hv.z + wv.w * hv.w;
        wv = Wrow[qb + i + 3]; hv = hrow[qb + i + 3];
        a3 += wv.x * hv.x + wv.y * hv.y + wv.z * hv.z + wv.w * hv.w;
    }
    const float p = (a0 + a1) + (a2 + a3);
    if (kh == 1) part[rib][l] = p;
    __syncthreads();

    if (kh == 0)
        out[(size_t)b * Lc + l] = bl[l] + p + part[rib][l];
}

extern "C" void kernel_launch(void* const* d_in, const int* in_sizes, int n_in,
                              void* d_out, int out_size, void* d_ws, size_t ws_size,
                              hipStream_t stream) {
    const float* x    = (const float*)d_in[0];
    const float* a_in = (const float*)d_in[1];
    const float* b_in = (const float*)d_in[2];
    const float* a_h  = (const float*)d_in[3];
    const float* b_h  = (const float*)d_in[4];
    const float* W    = (const float*)d_in[5];
    const float* bl   = (const float*)d_in[6];
    float* out = (float*)d_out;

    dim3 grid(Bc / 4), block(512);
    kan_rnn_collapsed<<<grid, block, 0, stream>>>(x, a_in, b_in, a_h, b_h, W, bl, out);
}

// Round 6
// 10.815 us; speedup vs baseline: 1.0538x; 1.0538x over previous
//
#include <hip/hip_runtime.h>
#include <stdint.h>

// KANRNNEncoder: T=1024 scan has dependency horizon 2 (only h[:, :24] feeds
// the recurrence, and those columns are pure functions of x at the previous
// step). Entire scan collapses to a closed form over x[:, T-2:T, :].
//
// R1: W_lat staged in LDS (coalesced), lane-rotated dot.      14.2 -> 10.4 us
// R2: K-split via MORE BLOCKS: REGRESSED (18.9) — per-block W staging is the
//     fixed cost; waves must come from inside the block.
// R3: 512 thr (2 waves/SIMD), wave-pair K-split, gload_lds W.  -> 9.6 us
// R4: padded-W + uniform-hv: REGRESSED (11.4). Lesson: b128 LDS reads are
//     return-path-bound (1KB/instr writeback), broadcast saves nothing;
//     don't micro-tune banks blind. Reverted layout to R3's.
// R5: R3 structure, 1024 thr (16 waves = 4/SIMD): wave-QUAD K-split per row
//     (16 chunks/wave), staging over 16 waves, hT compute over 4 waves.

constexpr int Bc = 1024, Tc = 1024, Fc = 8, Hc = 256, Kc = 8, Lc = 64;

__device__ __forceinline__ float sigm(float v) {
    return 1.0f / (1.0f + __expf(-v));
}

__global__ __launch_bounds__(1024) void kan_rnn_collapsed(
    const float* __restrict__ x,     // (B,T,F)
    const float* __restrict__ a_in,  // (F,K) flat 64
    const float* __restrict__ b_in,  // (F,K)
    const float* __restrict__ a_h,   // (H,K) flat 2048
    const float* __restrict__ b_h,   // (H,K)
    const float* __restrict__ W,     // (L,H) 64x256
    const float* __restrict__ bl,    // (L,)
    float* __restrict__ out)         // (B,L)
{
    __shared__ float Ws[Lc * Hc];    // 64 KB, linear (R3 layout)
    __shared__ float hTs[4][Hc];     // 4 KB
    __shared__ float part[4][4][Lc]; // 4 KB: [row][kquarter][lane]
    const int t   = threadIdx.x;
    const int w   = t >> 6;          // wave 0..15
    const int l   = t & 63;          // lane
    const int rib = w >> 2;          // row-in-block 0..3
    const int kq  = w & 3;           // K-quarter 0..3
    const int b   = blockIdx.x * 4 + rib;

    // ---- async stage W -> LDS: 4 issues x 1024 threads x 16B = 64 KB ----
    {
        const char* gsrc = (const char*)W + t * 16;
        char*       ldst = (char*)&Ws[0] + t * 16;
        #pragma unroll
        for (int k = 0; k < 4; ++k) {
            __builtin_amdgcn_global_load_lds(
                (const __attribute__((address_space(1))) uint32_t*)(gsrc + k * 16384),
                (__attribute__((address_space(3))) uint32_t*)(ldst + k * 16384),
                16, 0, 0);
        }
    }

    // ---- closed-form hT, split across the row's wave quad ----
    const float* xb  = x + (size_t)b * Tc * Fc;
    const int    hp0 = l >> 3;
    if (kq == 0) {       // entry c = l (input basis @ T-1)
        const float x1 = xb[(Tc - 1) * Fc + hp0];
        hTs[rib][l] = sigm(2.0f * sigm(a_in[l] * (x1 - b_in[l])));
    } else {             // entries c = 64 + l + 64*m, m = kq-1 (hidden basis)
        const int   m  = kq - 1;
        const int   hp = hp0 + 8 * m;            // h' in 0..23
        const int   j  = l + 64 * m;             // j  in 0..191
        const float x2 = xb[(Tc - 2) * Fc + m];
        const float s  = sigm(2.0f * sigm(a_in[hp] * (x2 - b_in[hp])));
        hTs[rib][64 + j] = sigm(2.0f * sigm(a_h[j] * (s - b_h[j])));
    }
    __syncthreads();   // drains gload_lds (vmcnt) + hT writes (lgkm)

    // ---- quarter-dot: lane l accumulates W[l][kq-quarter] . hT[rib][same] ----
    // R3's rotation (16-chunk version): lanes spread over bank groups.
    const float4* Wrow = reinterpret_cast<const float4*>(Ws) + l * (Hc / 4);
    const float4* hrow = reinterpret_cast<const float4*>(hTs[rib]);
    const int qb = 16 * kq;
    float a0 = 0.f, a1 = 0.f, a2 = 0.f, a3 = 0.f;
    #pragma unroll
    for (int i = 0; i < 16; i += 4) {
        const int q0 = qb + ((i + 0 + l) & 15);
        const int q1 = qb + ((i + 1 + l) & 15);
        const int q2 = qb + ((i + 2 + l) & 15);
        const int q3 = qb + ((i + 3 + l) & 15);
        float4 wv, hv;
        wv = Wrow[q0]; hv = hrow[q0];
        a0 += wv.x * hv.x + wv.y * hv.y + wv.z * hv.z + wv.w * hv.w;
        wv = Wrow[q1]; hv = hrow[q1];
        a1 += wv.x * hv.x + wv.y * hv.y + wv.z * hv.z + wv.w * hv.w;
        wv = Wrow[q2]; hv = hrow[q2];
        a2 += wv.x * hv.x + wv.y * hv.y + wv.z * hv.z + wv.w * hv.w;
        wv = Wrow[q3]; hv = hrow[q3];
        a3 += wv.x * hv.x + wv.y * hv.y + wv.z * hv.z + wv.w * hv.w;
    }
    part[rib][kq][l] = (a0 + a1) + (a2 + a3);
    __syncthreads();

    if (kq == 0) {
        out[(size_t)b * Lc + l] = bl[l] + part[rib][0][l] + part[rib][1][l]
                                        + part[rib][2][l] + part[rib][3][l];
    }
}

extern "C" void kernel_launch(void* const* d_in, const int* in_sizes, int n_in,
                              void* d_out, int out_size, void* d_ws, size_t ws_size,
                              hipStream_t stream) {
    const float* x    = (const float*)d_in[0];
    const float* a_in = (const float*)d_in[1];
    const float* b_in = (const float*)d_in[2];
    const float* a_h  = (const float*)d_in[3];
    const float* b_h  = (const float*)d_in[4];
    const float* W    = (const float*)d_in[5];
    const float* bl   = (const float*)d_in[6];
    float* out = (float*)d_out;

    dim3 grid(Bc / 4), block(1024);
    kan_rnn_collapsed<<<grid, block, 0, stream>>>(x, a_in, b_in, a_h, b_h, W, bl, out);
}

// Round 7
// 9.780 us; speedup vs baseline: 1.1652x; 1.1058x over previous
//
#include <hip/hip_runtime.h>
#include <stdint.h>

// KANRNNEncoder: T=1024 scan has dependency horizon 2 (only h[:, :24] feeds
// the recurrence; those columns are pure functions of x at the previous
// step). Entire scan collapses to a closed form over x[:, T-2:T, :].
//
// R1: W_lat staged in LDS, lane-rotated dot.                  14.2 -> 10.4 us
// R2: K-split via MORE BLOCKS: REGRESSED (18.9) — per-block fixed cost rules.
// R3: 512 thr (2 waves/SIMD), wave-pair K-split, gload_lds W.  -> 9.6 us
// R4: padded-W + uniform-hv: REGRESSED (11.4) — b128 reads are return-path
//     bound; broadcast saves nothing on the data path.
// R5: 1024 thr (4 waves/SIMD): REGRESSED (10.8).
// R6: restructure to kill 7/8 of LDS traffic: hT lives lane-distributed in
//     VGPRs and is broadcast via v_readlane (wave-uniform per row); each
//     wave takes a K-EIGHTH for ALL 4 rows, so W is LDS-read exactly once
//     per block (64 KB total vs R3's 512 KB). Uniform-chunk W reads are
//     conflict-freed by a chunk XOR-swizzle (slot = q ^ (row&7)), staged
//     via global_load_lds with the inverse swizzle on the per-lane GLOBAL
//     source address (LDS dest stays linear — rule: swizzle both sides).

constexpr int Bc = 1024, Tc = 1024, Fc = 8, Hc = 256, Kc = 8, Lc = 64;

__device__ __forceinline__ float sigm(float v) {
    return 1.0f / (1.0f + __expf(-v));
}
__device__ __forceinline__ float rdlane(float v, int lane) {
    return __uint_as_float(__builtin_amdgcn_readlane(__float_as_uint(v), lane));
}

__global__ __launch_bounds__(512) void kan_rnn_collapsed(
    const float* __restrict__ x,     // (B,T,F)
    const float* __restrict__ a_in,  // (F,K) flat 64
    const float* __restrict__ b_in,  // (F,K)
    const float* __restrict__ a_h,   // (H,K) flat 2048
    const float* __restrict__ b_h,   // (H,K)
    const float* __restrict__ W,     // (L,H) 64x256
    const float* __restrict__ bl,    // (L,)
    float* __restrict__ out)         // (B,L)
{
    __shared__ float Ws[Lc * Hc];     // 64 KB; row l chunk q stored at slot q^(l&7)
    __shared__ float part[8][4][Lc];  // 8 KB: [wave][row][col]
    const int t  = threadIdx.x;
    const int w  = t >> 6;            // wave 0..7
    const int l  = t & 63;            // lane
    const int l7 = l & 7;

    // ---- stage W -> LDS, one 1KB row per issue, source pre-swizzled ----
    // LDS dest linear (base + lane*16); lane λ of issue for row r receives
    // global chunk (λ ^ (r&7)) — so LDS slot s holds chunk s^(r&7).
    {
        #pragma unroll
        for (int k = 0; k < 8; ++k) {
            const int r  = w * 8 + k;       // wave-uniform row id
            const int gq = l ^ (r & 7);     // per-lane global chunk (within 128B groups -> coalesced)
            __builtin_amdgcn_global_load_lds(
                (const __attribute__((address_space(1))) uint32_t*)((const char*)W + r * 1024 + gq * 16),
                (__attribute__((address_space(3))) uint32_t*)((char*)Ws + r * 1024 + l * 16),
                16, 0, 0);
        }
    }

    // ---- hT word for this wave (all 4 rows), lane-distributed in VGPRs ----
    // Wave w consumes h-indices [32w, 32w+32) -> hT word widx = w>>1.
    // hh[r] at lane λ holds hT_r[64*widx + λ].
    const int widx = w >> 1;
    const float* xb = x + (size_t)(blockIdx.x * 4) * Tc * Fc;   // block's row 0
    float hh[4];
    if (widx == 0) {          // input-basis entries: c = lane
        #pragma unroll
        for (int r = 0; r < 4; ++r) {
            const float x1 = xb[r * Tc * Fc + (Tc - 1) * Fc + (l >> 3)];
            hh[r] = sigm(2.0f * sigm(a_in[l] * (x1 - b_in[l])));
        }
    } else {                  // hidden-basis entries: c = 64 + 64m + lane, m = widx-1
        const int m = widx - 1, hp = (l >> 3) + 8 * m, j = l + 64 * m;
        const float ai = a_in[hp], bi = b_in[hp], ah = a_h[j], bh = b_h[j];
        #pragma unroll
        for (int r = 0; r < 4; ++r) {
            const float x2 = xb[r * Tc * Fc + (Tc - 2) * Fc + m];
            const float s  = sigm(2.0f * sigm(ai * (x2 - bi)));
            hh[r] = sigm(2.0f * sigm(ah * (s - bh)));
        }
    }
    __syncthreads();   // drains gload_lds (vmcnt) before any Ws read

    // ---- dot: wave w covers chunks q = 8w..8w+7 for ALL 4 rows ----
    // wv read: lane l, row l, slot q^(l&7): banks 4*((q^(l&7))&7) -> 8 lanes
    // per bank-quad = 1KB/instr floor, conflict-free. hT via readlane (SGPR).
    float acc0 = 0.f, acc1 = 0.f, acc2 = 0.f, acc3 = 0.f;
    const int qbase = 8 * w, lbase = 32 * (w & 1);
    #pragma unroll
    for (int qq = 0; qq < 8; ++qq) {
        const int q = qbase + qq;
        const float4 wv = *reinterpret_cast<const float4*>(Ws + l * Hc + ((q ^ l7) << 2));
        #pragma unroll
        for (int j = 0; j < 4; ++j) {
            const int   lane = lbase + 4 * qq + j;
            const float wj = (j == 0) ? wv.x : (j == 1) ? wv.y : (j == 2) ? wv.z : wv.w;
            acc0 += wj * rdlane(hh[0], lane);
            acc1 += wj * rdlane(hh[1], lane);
            acc2 += wj * rdlane(hh[2], lane);
            acc3 += wj * rdlane(hh[3], lane);
        }
    }
    part[w][0][l] = acc0;  part[w][1][l] = acc1;
    part[w][2][l] = acc2;  part[w][3][l] = acc3;
    __syncthreads();

    // ---- combine: wave w (<4) owns row w ----
    if (w < 4) {
        float s = bl[l];
        #pragma unroll
        for (int wp = 0; wp < 8; ++wp) s += part[wp][w][l];
        out[(size_t)(blockIdx.x * 4 + w) * Lc + l] = s;
    }
}

extern "C" void kernel_launch(void* const* d_in, const int* in_sizes, int n_in,
                              void* d_out, int out_size, void* d_ws, size_t ws_size,
                              hipStream_t stream) {
    const float* x    = (const float*)d_in[0];
    const float* a_in = (const float*)d_in[1];
    const float* b_in = (const float*)d_in[2];
    const float* a_h  = (const float*)d_in[3];
    const float* b_h  = (const float*)d_in[4];
    const float* W    = (const float*)d_in[5];
    const float* bl   = (const float*)d_in[6];
    float* out = (float*)d_out;

    dim3 grid(Bc / 4), block(512);
    kan_rnn_collapsed<<<grid, block, 0, stream>>>(x, a_in, b_in, a_h, b_h, W, bl, out);
}